// Round 9
// baseline (311.688 us; speedup 1.0000x reference)
//
#include <hip/hip_runtime.h>
#include <hip/hip_bf16.h>

// MetaNetImageEncoder on MI355X — round 12.
// Post-mortem r11: gemm2c fusion neutral (285.2->289.5, within noise) —
// tail REVERTED to r10-measured best. r12 runs the decisive gemm_pool probe:
// the non-MIX B path moves only 4KB/iter through LDS (breg->ds_write->lgkm
// drain->barrier->ds_read) when each wave could load its MFMA B-fragments
// DIRECTLY into registers (16B/lane, 64B-coalesced rows, L2-resident),
// double-buffered one iter ahead under the existing counted vmcnt.
//   k_gemm_pool_dir (phase A): B in registers, no BslU, no lgkm, B decoupled
//     from the barrier; unroll-x2 for static reg parity (rule #20).
//   k_gemm_pool_mix (phase B): r10 body verbatim (frozen, separate kernel).
// Discriminator: dir 50-62us => B-LDS coupling was the cost (port MIX via
// premixed per-sample weights next); dir flat => A-spine is the floor.
//
// MFMA 16x16x32 bf16 layouts (learn_hip m89):
//   A-frag: A[m=lane&15][k=(lane>>4)*8+j], B-frag: B[k=(lane>>4)*8+j][n=lane&15]
//   C/D:    col=lane&15, row=(lane>>4)*4+reg

typedef __bf16 bf16x8 __attribute__((ext_vector_type(8)));
typedef float f32x4 __attribute__((ext_vector_type(4)));
typedef __hip_bfloat16 bf16;

struct alignas(16) BF8 { bf16 h[8]; };

constexpr int BATCH = 64;
constexpr int NP    = 196;
constexpr int NPAD  = 256;
constexpr int DIM   = 768;
constexpr int NT    = 8;
constexpr size_t MSZ = (size_t)DIM * DIM;

__device__ __forceinline__ void async_cp16(const void* g, void* l) {
  __builtin_amdgcn_global_load_lds(
      (const __attribute__((address_space(1))) uint32_t*)g,
      (__attribute__((address_space(3))) uint32_t*)l, 16, 0, 0);
}

#define WAITVM(N) asm volatile("s_waitcnt vmcnt(" #N ")" ::: "memory")

// ---------------- K1: fused patchify(+cast, pad) and weight transpose(+cast) ----------------
constexpr int PREP_PATCH_BLOCKS = (BATCH * NPAD * (DIM / 4)) / 256;   // 12288
constexpr int PREP_TRANS_BLOCKS = 24 * 24 * 18;                       // 10368

__global__ void k_prep(const float* __restrict__ x, bf16* __restrict__ A,
                       const float* __restrict__ W1, const float* __restrict__ dW1,
                       const float* __restrict__ W2, const float* __restrict__ dW2,
                       bf16* __restrict__ WT) {
  __shared__ float tile[32][33];
  int blk = blockIdx.x;
  int tid = threadIdx.x;
  if (blk < PREP_PATCH_BLOCKS) {
    int idx  = blk * 256 + tid;
    int col4 = idx % (DIM / 4);
    int row  = idx / (DIM / 4);
    int d = col4 * 4;
    int b = row >> 8;
    int n = row & 255;
    bf16 tmp[4];
    if (n < NP) {
      int hp = n / 14, wp = n % 14;
      int c  = d >> 8;
      int rr = d & 255;
      int i = rr >> 4, j = rr & 15;
      const float* src = x + ((((size_t)b * 3 + c) * 224 + hp * 16 + i) * 224 + wp * 16 + j);
      float4 f = *(const float4*)src;
      tmp[0] = __float2bfloat16(f.x);
      tmp[1] = __float2bfloat16(f.y);
      tmp[2] = __float2bfloat16(f.z);
      tmp[3] = __float2bfloat16(f.w);
    } else {
      tmp[0] = tmp[1] = tmp[2] = tmp[3] = __float2bfloat16(0.0f);
    }
    *(ushort4*)(A + (size_t)row * DIM + d) = *(ushort4*)tmp;
  } else {
    int tb  = blk - PREP_PATCH_BLOCKS;
    int mat = tb / 576;
    int rem = tb % 576;
    int n0 = (rem % 24) * 32;
    int k0 = (rem / 24) * 32;
    const float* src;
    if      (mat == 0) src = W1;
    else if (mat <= 8) src = dW1 + (size_t)(mat - 1) * MSZ;
    else if (mat == 9) src = W2;
    else               src = dW2 + (size_t)(mat - 10) * MSZ;
    int tx = tid & 31, ty = tid >> 5;
#pragma unroll
    for (int r = ty; r < 32; r += 8)
      tile[r][tx] = src[(size_t)(k0 + r) * DIM + n0 + tx];
    __syncthreads();
    bf16* dst = WT + (size_t)mat * MSZ;
#pragma unroll
    for (int r = ty; r < 32; r += 8)
      dst[(size_t)(n0 + r) * DIM + k0 + tx] = __float2bfloat16(tile[tx][r]);
  }
}

// ---------------- K3a: phase-A GEMM + relu + masked column-mean — register-direct B ---------
// grid (64, 12) = 768 blocks, 3/CU at 43KB LDS. BM=224, BN=64, BK=32, 24 iters.
// A: async global_load_lds, triple-buffered, staged 2 ahead (r10 spine).
// B: per-wave direct global->VGPR fragments, double-buffered 1 ahead (16 VGPR).
// Counted vmcnt covers BOTH: per iter issue B(kt+1)[4] then A(kt+2)[4/3];
// wait vmcnt(4/3) completes A(kt+1)+B(kt+1), leaves A(kt+2) in flight.
__global__ __launch_bounds__(256, 3)
void k_gemm_pool_dir(const bf16* __restrict__ A,    // [64*256, 768]
                     const bf16* __restrict__ WT,   // mat 0 = W1T
                     const float* __restrict__ b1,
                     float* __restrict__ pooled) {  // f32 [64][768]
  __shared__ uint4 AslU[3][896];   // 224 rows x 4 granules x 16B, x3 bufs = 42KB
  __shared__ float red[256];

  int b  = blockIdx.x;
  int n0 = blockIdx.y * 64;
  int tid = threadIdx.x;
  int wave = tid >> 6, lane = tid & 63;
  int quad = lane >> 4, l16 = lane & 15;

  const bf16* Ag = A + (size_t)b * NPAD * DIM;
  f32x4 acc[4][4] = {};

  // ---- A stage (r10 spine): 896 granules; waves 0,1: 4 instrs, waves 2,3: 3
  int gbase = (wave < 2) ? wave * 256 : 512 + (wave - 2) * 192;
  int gcnt  = (wave < 2) ? 4 : 3;
  int aoff[4];
#pragma unroll
  for (int i = 0; i < 4; i++) {
    int s = gbase + i * 64 + lane;
    int p = s >> 3, u = (s & 7) ^ (p & 7);
    int r = 2 * p + (u >> 2), c = u & 3;
    aoff[i] = r * DIM + c * 8;
  }
  auto stage_a = [&](int buf, int kt) {
    const bf16* Ak = Ag + kt * 32;
#pragma unroll
    for (int i = 0; i < 4; i++) {
      if (i < gcnt)
        async_cp16(Ak + aoff[i], (void*)&AslU[buf][gbase + i * 64]);
    }
  };
  auto gslot = [&](int row, int kq) {
    return (size_t)((row >> 1) * 8 + ((4 * (row & 1) + kq) ^ ((row >> 1) & 7)));
  };

  // ---- B: per-lane fragment pointers (16B each, 64B-coalesced per row group)
  const bf16* Bp[4];
#pragma unroll
  for (int nf = 0; nf < 4; nf++)
    Bp[nf] = WT + (size_t)(n0 + nf * 16 + l16) * DIM + quad * 8;

  bf16x8 bfrA[4], bfrB[4];

  // ---- prologue: A(0),A(1) in flight; B(0) -> bfrA; full drain once
  stage_a(0, 0);
  stage_a(1, 1);
#pragma unroll
  for (int nf = 0; nf < 4; nf++) bfrA[nf] = *(const bf16x8*)(Bp[nf]);
  WAITVM(0);
  __builtin_amdgcn_sched_barrier(0);

  int bufA = 0, stgA = 2;

  // one iteration; CUR holds B(kt), NXT receives B(kt+1)
#define GPD_ITER(KT, CUR, NXT)                                                 \
  {                                                                            \
    __builtin_amdgcn_s_barrier();                                              \
    if ((KT) < 23) {                                                           \
      const bf16* bsrc = WT + ((KT) + 1) * 32;                                 \
      _Pragma("unroll")                                                        \
      for (int nf = 0; nf < 4; nf++)                                           \
        NXT[nf] = *(const bf16x8*)(Bp[nf] + ((KT) + 1) * 32 - quad * 8         \
                                   + quad * 8);                                \
      (void)bsrc;                                                              \
    }                                                                          \
    __builtin_amdgcn_sched_barrier(0);                                         \
    if ((KT) < 22) stage_a(stgA, (KT) + 2);                                    \
    __builtin_amdgcn_sched_barrier(0);                                         \
    const bf16* As = (const bf16*)AslU[bufA];                                  \
    __builtin_amdgcn_s_setprio(1);                                             \
    _Pragma("unroll")                                                          \
    for (int mf = 0; mf < 4; mf++) {                                           \
      if (wave * 64 + mf * 16 < 224) {                                         \
        int arow = wave * 64 + mf * 16 + l16;                                  \
        bf16x8 af = *(const bf16x8*)(As + gslot(arow, quad) * 8);              \
        _Pragma("unroll")                                                      \
        for (int nf = 0; nf < 4; nf++)                                         \
          acc[mf][nf] = __builtin_amdgcn_mfma_f32_16x16x32_bf16(               \
              af, CUR[nf], acc[mf][nf], 0, 0, 0);                              \
      }                                                                        \
    }                                                                          \
    __builtin_amdgcn_s_setprio(0);                                             \
    if ((KT) < 22) {                                                           \
      if (wave < 2) WAITVM(4); else WAITVM(3);                                 \
    } else if ((KT) < 23) {                                                    \
      WAITVM(0);                                                               \
    }                                                                          \
    __builtin_amdgcn_sched_barrier(0);                                         \
    bufA = (bufA == 2) ? 0 : bufA + 1;                                         \
    stgA = (stgA == 2) ? 0 : stgA + 1;                                         \
  }

  for (int kt = 0; kt < 24; kt += 2) {
    GPD_ITER(kt, bfrA, bfrB);
    GPD_ITER(kt + 1, bfrB, bfrA);
  }
#undef GPD_ITER

  // ---- epilogue: relu(acc + bias), mask pad rows, column sums
  int m0 = wave * 64;
  float colsum[4];
#pragma unroll
  for (int nf = 0; nf < 4; nf++) {
    float bias = b1[n0 + nf * 16 + l16];
    float s = 0.0f;
#pragma unroll
    for (int mf = 0; mf < 4; mf++) {
      int rbase = m0 + mf * 16 + quad * 4;
#pragma unroll
      for (int r = 0; r < 4; r++) {
        if (rbase + r < NP) s += fmaxf(acc[mf][nf][r] + bias, 0.0f);
      }
    }
    s += __shfl_xor(s, 16, 64);
    s += __shfl_xor(s, 32, 64);
    colsum[nf] = s;
  }
  if (lane < 16) {
#pragma unroll
    for (int nf = 0; nf < 4; nf++) red[wave * 64 + nf * 16 + lane] = colsum[nf];
  }
  __syncthreads();
  if (tid < 64) {
    float s = red[tid] + red[64 + tid] + red[128 + tid] + red[192 + tid];
    pooled[(size_t)b * DIM + n0 + tid] = s * (1.0f / 196.0f);
  }
}

// ---------------- K3b: phase-B GEMM (inline mix) — r10 body verbatim [FROZEN] ---------------
__global__ __launch_bounds__(256, 3)
void k_gemm_pool_mix(const bf16* __restrict__ A,    // [64*256, 768]
                     const bf16* __restrict__ WT,   // mats 0..8 = W1T, dW1T[8]
                     const float* __restrict__ b1,
                     const float* __restrict__ db1,
                     const float* __restrict__ coefs,  // [64][8]
                     float* __restrict__ pooled) {     // f32 [64][768]
  __shared__ uint4 AslU[3][896];
  __shared__ uint4 BslU[2][256];

  int b  = blockIdx.x;
  int n0 = blockIdx.y * 64;
  int tid = threadIdx.x;
  int wave = tid >> 6, lane = tid & 63;
  int quad = lane >> 4, l16 = lane & 15;

  float cr[NT];
#pragma unroll
  for (int t = 0; t < NT; t++) cr[t] = coefs[b * NT + t];

  const bf16* Ag = A + (size_t)b * NPAD * DIM;
  f32x4 acc[4][4] = {};

  int gbase = (wave < 2) ? wave * 256 : 512 + (wave - 2) * 192;
  int gcnt  = (wave < 2) ? 4 : 3;
  int aoff[4];
#pragma unroll
  for (int i = 0; i < 4; i++) {
    int s = gbase + i * 64 + lane;
    int p = s >> 3, u = (s & 7) ^ (p & 7);
    int r = 2 * p + (u >> 2), c = u & 3;
    aoff[i] = r * DIM + c * 8;
  }
  auto stage_a = [&](int buf, int kt) {
    const bf16* Ak = Ag + kt * 32;
#pragma unroll
    for (int i = 0; i < 4; i++) {
      if (i < gcnt)
        async_cp16(Ak + aoff[i], (void*)&AslU[buf][gbase + i * 64]);
    }
  };

  int bp = tid >> 3, bu = (tid & 7) ^ (bp & 7);
  int brow_st = 2 * bp + (bu >> 2), bcol_st = bu & 3;
  const bf16* Wrow = WT + (size_t)(n0 + brow_st) * DIM + bcol_st * 8;

  BF8 wreg[9];
  auto breg_load = [&](int kt) {
    const bf16* p0 = Wrow + kt * 32;
    wreg[0] = *(const BF8*)p0;
#pragma unroll
    for (int t = 0; t < NT; t++)
      wreg[1 + t] = *(const BF8*)(p0 + (size_t)(1 + t) * MSZ);
  };
  auto breg_write = [&](int buf) {
    float m[8];
#pragma unroll
    for (int j = 0; j < 8; j++) m[j] = __bfloat162float(wreg[0].h[j]);
#pragma unroll
    for (int t = 0; t < NT; t++) {
      float cc = cr[t];
#pragma unroll
      for (int j = 0; j < 8; j++) m[j] += cc * __bfloat162float(wreg[1 + t].h[j]);
    }
    BF8 o;
#pragma unroll
    for (int j = 0; j < 8; j++) o.h[j] = __float2bfloat16(m[j]);
    BslU[buf][tid] = *(uint4*)&o;
  };

  auto gslot = [&](int row, int kq) {
    return (size_t)((row >> 1) * 8 + ((4 * (row & 1) + kq) ^ ((row >> 1) & 7)));
  };

  stage_a(0, 0);
  stage_a(1, 1);
  breg_load(0);
  WAITVM(0);
  __builtin_amdgcn_sched_barrier(0);
  breg_write(0);
  asm volatile("s_waitcnt lgkmcnt(0)" ::: "memory");

  int bufA = 0, stgA = 2, bufB = 0;
  for (int kt = 0; kt < 24; kt++) {
    __builtin_amdgcn_s_barrier();
    if (kt < 23) breg_load(kt + 1);
    __builtin_amdgcn_sched_barrier(0);
    if (kt < 22) stage_a(stgA, kt + 2);
    __builtin_amdgcn_sched_barrier(0);
    const bf16* As = (const bf16*)AslU[bufA];
    const bf16* Bs = (const bf16*)BslU[bufB];
    bf16x8 bfr[4];
#pragma unroll
    for (int nf = 0; nf < 4; nf++) {
      int brow = nf * 16 + l16;
      bfr[nf] = *(const bf16x8*)(Bs + gslot(brow, quad) * 8);
    }
    __builtin_amdgcn_s_setprio(1);
#pragma unroll
    for (int mf = 0; mf < 4; mf++) {
      if (wave * 64 + mf * 16 < 224) {
        int arow = wave * 64 + mf * 16 + l16;
        bf16x8 af = *(const bf16x8*)(As + gslot(arow, quad) * 8);
#pragma unroll
        for (int nf = 0; nf < 4; nf++)
          acc[mf][nf] = __builtin_amdgcn_mfma_f32_16x16x32_bf16(af, bfr[nf], acc[mf][nf], 0, 0, 0);
      }
    }
    __builtin_amdgcn_s_setprio(0);
    if (kt < 22) {
      if (wave < 2) WAITVM(4); else WAITVM(3);
    } else if (kt < 23) {
      WAITVM(0);
    }
    __builtin_amdgcn_sched_barrier(0);
    if (kt < 23) {
      breg_write(bufB ^ 1);
      asm volatile("s_waitcnt lgkmcnt(0)" ::: "memory");
    }
    bufA = (bufA == 2) ? 0 : bufA + 1;
    stgA = (stgA == 2) ? 0 : stgA + 1;
    bufB ^= 1;
  }

  float* red = (float*)&BslU[0][0];
  int m0 = wave * 64;
  float colsum[4];
#pragma unroll
  for (int nf = 0; nf < 4; nf++) {
    int col = n0 + nf * 16 + l16;
    float bias = b1[col];
#pragma unroll
    for (int t = 0; t < NT; t++) bias += cr[t] * db1[t * DIM + col];
    float s = 0.0f;
#pragma unroll
    for (int mf = 0; mf < 4; mf++) {
      int rbase = m0 + mf * 16 + quad * 4;
#pragma unroll
      for (int r = 0; r < 4; r++) {
        if (rbase + r < NP) s += fmaxf(acc[mf][nf][r] + bias, 0.0f);
      }
    }
    s += __shfl_xor(s, 16, 64);
    s += __shfl_xor(s, 32, 64);
    colsum[nf] = s;
  }
  if (lane < 16) {
#pragma unroll
    for (int nf = 0; nf < 4; nf++) red[wave * 64 + nf * 16 + lane] = colsum[nf];
  }
  __syncthreads();
  if (tid < 64) {
    float s = red[tid] + red[64 + tid] + red[128 + tid] + red[192 + tid];
    pooled[(size_t)b * DIM + n0 + tid] = s * (1.0f / 196.0f);
  }
}

// ---------------- K5a: base partials, K-split x4 ----------------
__global__ __launch_bounds__(256, 2)
void k_gemm2_ksplit(const float* __restrict__ Af,    // [64][768] f32 (pooledA)
                    const bf16* __restrict__ WT,     // mat 9 = W2T
                    float* __restrict__ basep) {     // [4][64][768]
  __shared__ uint4 AslU[64 * 8];
  __shared__ uint4 BslU[64 * 8];
  int n0  = blockIdx.x * 64;
  int kz  = blockIdx.y;
  int tid = threadIdx.x, wave = tid >> 6, lane = tid & 63;
  int quad = lane >> 4, l16 = lane & 15;
  f32x4 acc[4] = {};
  const bf16* Wm = WT + (size_t)9 * MSZ;
  for (int k0 = kz * 192; k0 < kz * 192 + 192; k0 += 64) {
#pragma unroll
    for (int i = 0; i < 2; i++) {
      int g = tid + i * 256;
      int r = g >> 3, c = g & 7;
      const float* src = Af + (size_t)r * DIM + k0 + c * 8;
      float4 xa = ((const float4*)src)[0];
      float4 xb = ((const float4*)src)[1];
      BF8 o;
      o.h[0] = __float2bfloat16(xa.x); o.h[1] = __float2bfloat16(xa.y);
      o.h[2] = __float2bfloat16(xa.z); o.h[3] = __float2bfloat16(xa.w);
      o.h[4] = __float2bfloat16(xb.x); o.h[5] = __float2bfloat16(xb.y);
      o.h[6] = __float2bfloat16(xb.z); o.h[7] = __float2bfloat16(xb.w);
      AslU[r * 8 + (c ^ (r & 7))] = *(uint4*)&o;
      BslU[r * 8 + (c ^ (r & 7))] = *(const uint4*)(Wm + (size_t)(n0 + r) * DIM + k0 + c * 8);
    }
    __syncthreads();
    const bf16* As = (const bf16*)AslU;
    const bf16* Bs = (const bf16*)BslU;
#pragma unroll
    for (int ks = 0; ks < 2; ks++) {
      int brow = wave * 16 + l16;
      bf16x8 bfr = *(const bf16x8*)(Bs + (size_t)(brow * 8 + ((ks * 4 + quad) ^ (brow & 7))) * 8);
#pragma unroll
      for (int mf = 0; mf < 4; mf++) {
        int arow = mf * 16 + l16;
        bf16x8 af = *(const bf16x8*)(As + (size_t)(arow * 8 + ((ks * 4 + quad) ^ (arow & 7))) * 8);
        acc[mf] = __builtin_amdgcn_mfma_f32_16x16x32_bf16(af, bfr, acc[mf], 0, 0, 0);
      }
    }
    __syncthreads();
  }
#pragma unroll
  for (int mf = 0; mf < 4; mf++) {
#pragma unroll
    for (int r = 0; r < 4; r++) {
      int row = mf * 16 + quad * 4 + r;
      int col = n0 + wave * 16 + l16;
      basep[((size_t)kz * 64 + row) * DIM + col] = acc[mf][r];
    }
  }
}

// ---------------- K6: MetaNet ----------------
__global__ void k_metanet(const float* __restrict__ basep,  // [4][64][768]
                          const float* __restrict__ b2,
                          const float* __restrict__ mw1, const float* __restrict__ mb1,
                          const float* __restrict__ mw2, const float* __restrict__ mb2,
                          float* __restrict__ coefs) {      // [64][8]
  __shared__ float bl[DIM];
  __shared__ float hl[192];
  int b = blockIdx.x, tid = threadIdx.x;   // 192 threads
  const size_t ZS = (size_t)64 * DIM;
  for (int i = tid; i < DIM; i += 192) {
    size_t o = (size_t)b * DIM + i;
    bl[i] = basep[o] + basep[ZS + o] + basep[2 * ZS + o] + basep[3 * ZS + o] + b2[i];
  }
  __syncthreads();
  float s = mb1[tid];
  for (int k = 0; k < DIM; k++) s += bl[k] * mw1[(size_t)k * 192 + tid];
  hl[tid] = fmaxf(s, 0.0f);
  __syncthreads();
  if (tid < NT) {
    float c = mb2[tid];
    for (int j = 0; j < 192; j++) c += hl[j] * mw2[(size_t)j * NT + tid];
    coefs[b * NT + tid] = c;
  }
}

// ---------------- K5: small GEMM, M=64: Y[mat] = Af(f32->bf16) @ WT[9+mat] ------------
__global__ __launch_bounds__(256, 2)
void k_gemm2(const float* __restrict__ Af,    // [64][768] f32
             const bf16* __restrict__ WT,
             float* __restrict__ Y) {         // [9][64][768]
  __shared__ uint4 AslU[64 * 8];
  __shared__ uint4 BslU[64 * 8];
  int n0  = blockIdx.x * 64;
  int mat = blockIdx.y;
  int tid = threadIdx.x, wave = tid >> 6, lane = tid & 63;
  int quad = lane >> 4, l16 = lane & 15;
  f32x4 acc[4] = {};
  const bf16* Wm = WT + (size_t)(9 + mat) * MSZ;
  for (int k0 = 0; k0 < DIM; k0 += 64) {
#pragma unroll
    for (int i = 0; i < 2; i++) {
      int g = tid + i * 256;
      int r = g >> 3, c = g & 7;
      const float* src = Af + (size_t)r * DIM + k0 + c * 8;
      float4 xa = ((const float4*)src)[0];
      float4 xb = ((const float4*)src)[1];
      BF8 o;
      o.h[0] = __float2bfloat16(xa.x); o.h[1] = __float2bfloat16(xa.y);
      o.h[2] = __float2bfloat16(xa.z); o.h[3] = __float2bfloat16(xa.w);
      o.h[4] = __float2bfloat16(xb.x); o.h[5] = __float2bfloat16(xb.y);
      o.h[6] = __float2bfloat16(xb.z); o.h[7] = __float2bfloat16(xb.w);
      AslU[r * 8 + (c ^ (r & 7))] = *(uint4*)&o;
      BslU[r * 8 + (c ^ (r & 7))] = *(const uint4*)(Wm + (size_t)(n0 + r) * DIM + k0 + c * 8);
    }
    __syncthreads();
    const bf16* As = (const bf16*)AslU;
    const bf16* Bs = (const bf16*)BslU;
#pragma unroll
    for (int ks = 0; ks < 2; ks++) {
      int brow = wave * 16 + l16;
      bf16x8 bfr = *(const bf16x8*)(Bs + (size_t)(brow * 8 + ((ks * 4 + quad) ^ (brow & 7))) * 8);
#pragma unroll
      for (int mf = 0; mf < 4; mf++) {
        int arow = mf * 16 + l16;
        bf16x8 af = *(const bf16x8*)(As + (size_t)(arow * 8 + ((ks * 4 + quad) ^ (arow & 7))) * 8);
        acc[mf] = __builtin_amdgcn_mfma_f32_16x16x32_bf16(af, bfr, acc[mf], 0, 0, 0);
      }
    }
    __syncthreads();
  }
#pragma unroll
  for (int mf = 0; mf < 4; mf++) {
#pragma unroll
    for (int r = 0; r < 4; r++) {
      int row = mf * 16 + quad * 4 + r;
      int col = n0 + wave * 16 + l16;
      Y[((size_t)mat * 64 + row) * DIM + col] = acc[mf][r];
    }
  }
}

// ---------------- K7: combine ----------------
__global__ void k_combine(const float* __restrict__ Y,
                          const float* __restrict__ coefs,
                          const float* __restrict__ b2,
                          const float* __restrict__ db2,
                          float* __restrict__ out) {
  int idx = blockIdx.x * 256 + threadIdx.x;
  int b = idx / DIM, e = idx % DIM;
  float v = Y[(size_t)b * DIM + e] + b2[e];
#pragma unroll
  for (int t = 0; t < NT; t++) {
    float c = coefs[b * NT + t];
    v += c * (Y[((size_t)(1 + t) * 64 + b) * DIM + e] + db2[(size_t)t * DIM + e]);
  }
  out[idx] = v;
}

extern "C" void kernel_launch(void* const* d_in, const int* in_sizes, int n_in,
                              void* d_out, int out_size, void* d_ws, size_t ws_size,
                              hipStream_t stream) {
  const float* x   = (const float*)d_in[0];
  const float* W1  = (const float*)d_in[1];
  const float* b1  = (const float*)d_in[2];
  const float* W2  = (const float*)d_in[3];
  const float* b2  = (const float*)d_in[4];
  const float* dW1 = (const float*)d_in[5];
  const float* db1 = (const float*)d_in[6];
  const float* dW2 = (const float*)d_in[7];
  const float* db2 = (const float*)d_in[8];
  const float* mw1 = (const float*)d_in[9];
  const float* mb1 = (const float*)d_in[10];
  const float* mw2 = (const float*)d_in[11];
  const float* mb2 = (const float*)d_in[12];
  float* out = (float*)d_out;
  (void)in_sizes; (void)n_in; (void)out_size; (void)ws_size;

  // workspace layout (bytes) — total ~49.4 MB
  char* ws = (char*)d_ws;
  bf16*  A_bf    = (bf16*) (ws);                 // 25,165,824
  bf16*  WT      = (bf16*) (ws + 25165824);      // 21,233,664 -> 46,399,488
  float* pooledA = (float*)(ws + 46399488);      //    196,608 -> 46,596,096
  float* pooledB = (float*)(ws + 46596096);      //    196,608 -> 46,792,704
  float* coefs   = (float*)(ws + 46792704);      //      2,048 -> 46,794,752
  float* basep   = (float*)(ws + 46794752);      //    786,432 -> 47,581,184
  float* Y       = (float*)(ws + 47581184);      //  1,769,472 -> 49,350,656

  k_prep<<<dim3(PREP_PATCH_BLOCKS + PREP_TRANS_BLOCKS), 256, 0, stream>>>(
      x, A_bf, W1, dW1, W2, dW2, WT);
  // phase A (register-direct B probe)
  k_gemm_pool_dir<<<dim3(BATCH, DIM / 64), 256, 0, stream>>>(A_bf, WT, b1, pooledA);
  k_gemm2_ksplit<<<dim3(DIM / 64, 4), 256, 0, stream>>>(pooledA, WT, basep);
  k_metanet<<<dim3(BATCH), 192, 0, stream>>>(basep, b2, mw1, mb1, mw2, mb2, coefs);
  // phase B (inline mix, frozen r10 body)
  k_gemm_pool_mix<<<dim3(BATCH, DIM / 64), 256, 0, stream>>>(A_bf, WT, b1, db1, coefs, pooledB);
  k_gemm2<<<dim3(DIM / 64, 9), 256, 0, stream>>>(pooledB, WT, Y);
  k_combine<<<dim3((BATCH * DIM) / 256), 256, 0, stream>>>(Y, coefs, b2, db2, out);
}

// Round 10
// 286.369 us; speedup vs baseline: 1.0884x; 1.0884x over previous
//
#include <hip/hip_runtime.h>
#include <hip/hip_bf16.h>

// MetaNetImageEncoder on MI355X — round 13.
// Post-mortem r12: register-direct B was SLOWER (~109us inferred vs 80;
// top-5 all mix, total arithmetic pins dir). Adding scattered per-lane VMEM
// loads degraded => the VMEM request path is the scarce resource. The 3
// co-resident blocks of a sample each re-stage the SAME A k-tile (54KB/CU/iter).
// r13 phase A: ONE 512-thread block per CU (grid 64x4, BN=192, 8 waves 2Mx4N):
// A staged once per CU (not 3x), B async-staged (12KB/192rows), per-CU staged
// volume 54->26KB/iter at identical MFMA work. Same depth-2 counted-vmcnt
// spine + pair-granule swizzle. acc[7][3]=84 VGPR. LDS 79.5KB.
// Phase B mix kernel frozen (77.8us measured r12); tail r10-exact.
// Discriminator: poolA 45-60us => VMEM-volume model right; flat => per-block
// latency chain, revert to r10 next round and stop.
//
// MFMA 16x16x32 bf16 layouts (learn_hip m89):
//   A-frag: A[m=lane&15][k=(lane>>4)*8+j], B-frag: B[k=(lane>>4)*8+j][n=lane&15]
//   C/D:    col=lane&15, row=(lane>>4)*4+reg

typedef __bf16 bf16x8 __attribute__((ext_vector_type(8)));
typedef float f32x4 __attribute__((ext_vector_type(4)));
typedef __hip_bfloat16 bf16;

struct alignas(16) BF8 { bf16 h[8]; };

constexpr int BATCH = 64;
constexpr int NP    = 196;
constexpr int NPAD  = 256;
constexpr int DIM   = 768;
constexpr int NT    = 8;
constexpr size_t MSZ = (size_t)DIM * DIM;

__device__ __forceinline__ void async_cp16(const void* g, void* l) {
  __builtin_amdgcn_global_load_lds(
      (const __attribute__((address_space(1))) uint32_t*)g,
      (__attribute__((address_space(3))) uint32_t*)l, 16, 0, 0);
}

#define WAITVM(N) asm volatile("s_waitcnt vmcnt(" #N ")" ::: "memory")

// ---------------- K1: fused patchify(+cast, pad) and weight transpose(+cast) ----------------
constexpr int PREP_PATCH_BLOCKS = (BATCH * NPAD * (DIM / 4)) / 256;   // 12288
constexpr int PREP_TRANS_BLOCKS = 24 * 24 * 18;                       // 10368

__global__ void k_prep(const float* __restrict__ x, bf16* __restrict__ A,
                       const float* __restrict__ W1, const float* __restrict__ dW1,
                       const float* __restrict__ W2, const float* __restrict__ dW2,
                       bf16* __restrict__ WT) {
  __shared__ float tile[32][33];
  int blk = blockIdx.x;
  int tid = threadIdx.x;
  if (blk < PREP_PATCH_BLOCKS) {
    int idx  = blk * 256 + tid;
    int col4 = idx % (DIM / 4);
    int row  = idx / (DIM / 4);
    int d = col4 * 4;
    int b = row >> 8;
    int n = row & 255;
    bf16 tmp[4];
    if (n < NP) {
      int hp = n / 14, wp = n % 14;
      int c  = d >> 8;
      int rr = d & 255;
      int i = rr >> 4, j = rr & 15;
      const float* src = x + ((((size_t)b * 3 + c) * 224 + hp * 16 + i) * 224 + wp * 16 + j);
      float4 f = *(const float4*)src;
      tmp[0] = __float2bfloat16(f.x);
      tmp[1] = __float2bfloat16(f.y);
      tmp[2] = __float2bfloat16(f.z);
      tmp[3] = __float2bfloat16(f.w);
    } else {
      tmp[0] = tmp[1] = tmp[2] = tmp[3] = __float2bfloat16(0.0f);
    }
    *(ushort4*)(A + (size_t)row * DIM + d) = *(ushort4*)tmp;
  } else {
    int tb  = blk - PREP_PATCH_BLOCKS;
    int mat = tb / 576;
    int rem = tb % 576;
    int n0 = (rem % 24) * 32;
    int k0 = (rem / 24) * 32;
    const float* src;
    if      (mat == 0) src = W1;
    else if (mat <= 8) src = dW1 + (size_t)(mat - 1) * MSZ;
    else if (mat == 9) src = W2;
    else               src = dW2 + (size_t)(mat - 10) * MSZ;
    int tx = tid & 31, ty = tid >> 5;
#pragma unroll
    for (int r = ty; r < 32; r += 8)
      tile[r][tx] = src[(size_t)(k0 + r) * DIM + n0 + tx];
    __syncthreads();
    bf16* dst = WT + (size_t)mat * MSZ;
#pragma unroll
    for (int r = ty; r < 32; r += 8)
      dst[(size_t)(n0 + r) * DIM + k0 + tx] = __float2bfloat16(tile[tx][r]);
  }
}

// ---------------- K3a: phase-A GEMM + relu + masked column-mean — 1 block/CU ----------------
// grid (64, 4) = 256 blocks x 512 threads (8 waves: wm=w&1 over M, wn=w>>1 over N).
// BM=224, BN=192, BK=32, 24 iters. A+B async-staged, triple-buffered, 2 ahead,
// counted vmcnt. Pair-granule swizzle g(r,c)=(r>>1)*8+((4*(r&1)+c)^((r>>1)&7));
// staging inverse for slot s: p=s>>3, u=(s&7)^(p&7), r=2p+(u>>2), c=u&3.
__global__ __launch_bounds__(512, 2)
void k_gemm_poolA(const bf16* __restrict__ A,    // [64*256, 768]
                  const bf16* __restrict__ WT,   // mat 0 = W1T
                  const float* __restrict__ b1,
                  float* __restrict__ pooled) {  // f32 [64][768]
  __shared__ uint4 AslU[3][896];   // 224 rows x 4 granules, x3 bufs = 42KB
  __shared__ uint4 BslU[3][768];   // 192 rows x 4 granules, x3 bufs = 36KB
  __shared__ float red[8][48];     // 1.5KB

  int b  = blockIdx.x;
  int n0 = blockIdx.y * 192;
  int tid = threadIdx.x;
  int w = tid >> 6, lane = tid & 63;
  int quad = lane >> 4, l16 = lane & 15;
  int wm = w & 1, wn = w >> 1;

  const bf16* Ag = A + (size_t)b * NPAD * DIM;
  const bf16* Bg = WT + (size_t)n0 * DIM;

  f32x4 acc[7][3] = {};

  // hoisted stage source offsets (swizzle inverse baked in)
  int off0, off1;
  {
    int s = w * 64 + lane;                   // slots 0..511 (all waves)
    int p = s >> 3, u = (s & 7) ^ (p & 7);
    off0 = (2 * p + (u >> 2)) * DIM + (u & 3) * 8;
    int s1 = 512 + w * 64 + lane;            // slots 512.. (A: w<6, B: w<4)
    int p1 = s1 >> 3, u1 = (s1 & 7) ^ (p1 & 7);
    off1 = (2 * p1 + (u1 >> 2)) * DIM + (u1 & 3) * 8;
  }
  auto stage_ab = [&](int buf, int kt) {
    const bf16* Ak = Ag + kt * 32;
    const bf16* Bk = Bg + kt * 32;
    async_cp16(Ak + off0, (void*)&AslU[buf][w * 64]);
    if (w < 6) async_cp16(Ak + off1, (void*)&AslU[buf][512 + w * 64]);
    async_cp16(Bk + off0, (void*)&BslU[buf][w * 64]);
    if (w < 4) async_cp16(Bk + off1, (void*)&BslU[buf][512 + w * 64]);
  };
  auto gslot = [&](int row, int kq) {
    return (size_t)((row >> 1) * 8 + ((4 * (row & 1) + kq) ^ ((row >> 1) & 7)));
  };

  // ---- prologue: tiles 0,1 staged; drain once
  stage_ab(0, 0);
  stage_ab(1, 1);
  WAITVM(0);
  __builtin_amdgcn_sched_barrier(0);

  // ---- K-loop: 24 iters, depth-2 counted pipeline
  int bufA = 0, stgA = 2;
  for (int kt = 0; kt < 24; kt++) {
    __builtin_amdgcn_s_barrier();    // tile kt complete in all lanes' queues
    if (kt < 22) stage_ab(stgA, kt + 2);
    __builtin_amdgcn_sched_barrier(0);
    const bf16* As = (const bf16*)AslU[bufA];
    const bf16* Bs = (const bf16*)BslU[bufA];
    bf16x8 bfr[3];
#pragma unroll
    for (int nf = 0; nf < 3; nf++) {
      int brow = wn * 48 + nf * 16 + l16;
      bfr[nf] = *(const bf16x8*)(Bs + gslot(brow, quad) * 8);
    }
    __builtin_amdgcn_s_setprio(1);
#pragma unroll
    for (int mf = 0; mf < 7; mf++) {
      int arow = wm * 112 + mf * 16 + l16;
      bf16x8 af = *(const bf16x8*)(As + gslot(arow, quad) * 8);
#pragma unroll
      for (int nf = 0; nf < 3; nf++)
        acc[mf][nf] = __builtin_amdgcn_mfma_f32_16x16x32_bf16(af, bfr[nf], acc[mf][nf], 0, 0, 0);
    }
    __builtin_amdgcn_s_setprio(0);
    // counted wait: completes batch(kt+1), leaves batch(kt+2) in flight
    if (kt < 22) {
      if (w < 4) WAITVM(4); else if (w < 6) WAITVM(3); else WAITVM(2);
    } else if (kt < 23) {
      WAITVM(0);
    }
    __builtin_amdgcn_sched_barrier(0);
    bufA = (bufA == 2) ? 0 : bufA + 1;
    stgA = (stgA == 2) ? 0 : stgA + 1;
  }

  // ---- epilogue: relu(acc + bias), mask pad rows, column sums
  float colsum[3];
#pragma unroll
  for (int nf = 0; nf < 3; nf++) {
    float bias = b1[n0 + wn * 48 + nf * 16 + l16];
    float s = 0.0f;
#pragma unroll
    for (int mf = 0; mf < 7; mf++) {
      int rbase = wm * 112 + mf * 16 + quad * 4;
#pragma unroll
      for (int r = 0; r < 4; r++) {
        if (rbase + r < NP) s += fmaxf(acc[mf][nf][r] + bias, 0.0f);
      }
    }
    s += __shfl_xor(s, 16, 64);
    s += __shfl_xor(s, 32, 64);
    colsum[nf] = s;
  }
  if (lane < 16) {
#pragma unroll
    for (int nf = 0; nf < 3; nf++) red[w][nf * 16 + lane] = colsum[nf];
  }
  __syncthreads();
  if (tid < 192) {
    int wn2 = tid / 48, off = tid % 48;
    float s = red[2 * wn2][off] + red[2 * wn2 + 1][off];
    pooled[(size_t)b * DIM + n0 + tid] = s * (1.0f / 196.0f);
  }
}

// ---------------- K3b: phase-B GEMM (inline mix) — r10 body verbatim [FROZEN, 77.8us] -------
__global__ __launch_bounds__(256, 3)
void k_gemm_pool_mix(const bf16* __restrict__ A,    // [64*256, 768]
                     const bf16* __restrict__ WT,   // mats 0..8 = W1T, dW1T[8]
                     const float* __restrict__ b1,
                     const float* __restrict__ db1,
                     const float* __restrict__ coefs,  // [64][8]
                     float* __restrict__ pooled) {     // f32 [64][768]
  __shared__ uint4 AslU[3][896];
  __shared__ uint4 BslU[2][256];

  int b  = blockIdx.x;
  int n0 = blockIdx.y * 64;
  int tid = threadIdx.x;
  int wave = tid >> 6, lane = tid & 63;
  int quad = lane >> 4, l16 = lane & 15;

  float cr[NT];
#pragma unroll
  for (int t = 0; t < NT; t++) cr[t] = coefs[b * NT + t];

  const bf16* Ag = A + (size_t)b * NPAD * DIM;
  f32x4 acc[4][4] = {};

  int gbase = (wave < 2) ? wave * 256 : 512 + (wave - 2) * 192;
  int gcnt  = (wave < 2) ? 4 : 3;
  int aoff[4];
#pragma unroll
  for (int i = 0; i < 4; i++) {
    int s = gbase + i * 64 + lane;
    int p = s >> 3, u = (s & 7) ^ (p & 7);
    int r = 2 * p + (u >> 2), c = u & 3;
    aoff[i] = r * DIM + c * 8;
  }
  auto stage_a = [&](int buf, int kt) {
    const bf16* Ak = Ag + kt * 32;
#pragma unroll
    for (int i = 0; i < 4; i++) {
      if (i < gcnt)
        async_cp16(Ak + aoff[i], (void*)&AslU[buf][gbase + i * 64]);
    }
  };

  int bp = tid >> 3, bu = (tid & 7) ^ (bp & 7);
  int brow_st = 2 * bp + (bu >> 2), bcol_st = bu & 3;
  const bf16* Wrow = WT + (size_t)(n0 + brow_st) * DIM + bcol_st * 8;

  BF8 wreg[9];
  auto breg_load = [&](int kt) {
    const bf16* p0 = Wrow + kt * 32;
    wreg[0] = *(const BF8*)p0;
#pragma unroll
    for (int t = 0; t < NT; t++)
      wreg[1 + t] = *(const BF8*)(p0 + (size_t)(1 + t) * MSZ);
  };
  auto breg_write = [&](int buf) {
    float m[8];
#pragma unroll
    for (int j = 0; j < 8; j++) m[j] = __bfloat162float(wreg[0].h[j]);
#pragma unroll
    for (int t = 0; t < NT; t++) {
      float cc = cr[t];
#pragma unroll
      for (int j = 0; j < 8; j++) m[j] += cc * __bfloat162float(wreg[1 + t].h[j]);
    }
    BF8 o;
#pragma unroll
    for (int j = 0; j < 8; j++) o.h[j] = __float2bfloat16(m[j]);
    BslU[buf][tid] = *(uint4*)&o;
  };

  auto gslot = [&](int row, int kq) {
    return (size_t)((row >> 1) * 8 + ((4 * (row & 1) + kq) ^ ((row >> 1) & 7)));
  };

  stage_a(0, 0);
  stage_a(1, 1);
  breg_load(0);
  WAITVM(0);
  __builtin_amdgcn_sched_barrier(0);
  breg_write(0);
  asm volatile("s_waitcnt lgkmcnt(0)" ::: "memory");

  int bufA = 0, stgA = 2, bufB = 0;
  for (int kt = 0; kt < 24; kt++) {
    __builtin_amdgcn_s_barrier();
    if (kt < 23) breg_load(kt + 1);
    __builtin_amdgcn_sched_barrier(0);
    if (kt < 22) stage_a(stgA, kt + 2);
    __builtin_amdgcn_sched_barrier(0);
    const bf16* As = (const bf16*)AslU[bufA];
    const bf16* Bs = (const bf16*)BslU[bufB];
    bf16x8 bfr[4];
#pragma unroll
    for (int nf = 0; nf < 4; nf++) {
      int brow = nf * 16 + l16;
      bfr[nf] = *(const bf16x8*)(Bs + gslot(brow, quad) * 8);
    }
    __builtin_amdgcn_s_setprio(1);
#pragma unroll
    for (int mf = 0; mf < 4; mf++) {
      if (wave * 64 + mf * 16 < 224) {
        int arow = wave * 64 + mf * 16 + l16;
        bf16x8 af = *(const bf16x8*)(As + gslot(arow, quad) * 8);
#pragma unroll
        for (int nf = 0; nf < 4; nf++)
          acc[mf][nf] = __builtin_amdgcn_mfma_f32_16x16x32_bf16(af, bfr[nf], acc[mf][nf], 0, 0, 0);
      }
    }
    __builtin_amdgcn_s_setprio(0);
    if (kt < 22) {
      if (wave < 2) WAITVM(4); else WAITVM(3);
    } else if (kt < 23) {
      WAITVM(0);
    }
    __builtin_amdgcn_sched_barrier(0);
    if (kt < 23) {
      breg_write(bufB ^ 1);
      asm volatile("s_waitcnt lgkmcnt(0)" ::: "memory");
    }
    bufA = (bufA == 2) ? 0 : bufA + 1;
    stgA = (stgA == 2) ? 0 : stgA + 1;
    bufB ^= 1;
  }

  float* red = (float*)&BslU[0][0];
  int m0 = wave * 64;
  float colsum[4];
#pragma unroll
  for (int nf = 0; nf < 4; nf++) {
    int col = n0 + nf * 16 + l16;
    float bias = b1[col];
#pragma unroll
    for (int t = 0; t < NT; t++) bias += cr[t] * db1[t * DIM + col];
    float s = 0.0f;
#pragma unroll
    for (int mf = 0; mf < 4; mf++) {
      int rbase = m0 + mf * 16 + quad * 4;
#pragma unroll
      for (int r = 0; r < 4; r++) {
        if (rbase + r < NP) s += fmaxf(acc[mf][nf][r] + bias, 0.0f);
      }
    }
    s += __shfl_xor(s, 16, 64);
    s += __shfl_xor(s, 32, 64);
    colsum[nf] = s;
  }
  if (lane < 16) {
#pragma unroll
    for (int nf = 0; nf < 4; nf++) red[wave * 64 + nf * 16 + lane] = colsum[nf];
  }
  __syncthreads();
  if (tid < 64) {
    float s = red[tid] + red[64 + tid] + red[128 + tid] + red[192 + tid];
    pooled[(size_t)b * DIM + n0 + tid] = s * (1.0f / 196.0f);
  }
}

// ---------------- K5a: base partials, K-split x4 ----------------
__global__ __launch_bounds__(256, 2)
void k_gemm2_ksplit(const float* __restrict__ Af,    // [64][768] f32 (pooledA)
                    const bf16* __restrict__ WT,     // mat 9 = W2T
                    float* __restrict__ basep) {     // [4][64][768]
  __shared__ uint4 AslU[64 * 8];
  __shared__ uint4 BslU[64 * 8];
  int n0  = blockIdx.x * 64;
  int kz  = blockIdx.y;
  int tid = threadIdx.x, wave = tid >> 6, lane = tid & 63;
  int quad = lane >> 4, l16 = lane & 15;
  f32x4 acc[4] = {};
  const bf16* Wm = WT + (size_t)9 * MSZ;
  for (int k0 = kz * 192; k0 < kz * 192 + 192; k0 += 64) {
#pragma unroll
    for (int i = 0; i < 2; i++) {
      int g = tid + i * 256;
      int r = g >> 3, c = g & 7;
      const float* src = Af + (size_t)r * DIM + k0 + c * 8;
      float4 xa = ((const float4*)src)[0];
      float4 xb = ((const float4*)src)[1];
      BF8 o;
      o.h[0] = __float2bfloat16(xa.x); o.h[1] = __float2bfloat16(xa.y);
      o.h[2] = __float2bfloat16(xa.z); o.h[3] = __float2bfloat16(xa.w);
      o.h[4] = __float2bfloat16(xb.x); o.h[5] = __float2bfloat16(xb.y);
      o.h[6] = __float2bfloat16(xb.z); o.h[7] = __float2bfloat16(xb.w);
      AslU[r * 8 + (c ^ (r & 7))] = *(uint4*)&o;
      BslU[r * 8 + (c ^ (r & 7))] = *(const uint4*)(Wm + (size_t)(n0 + r) * DIM + k0 + c * 8);
    }
    __syncthreads();
    const bf16* As = (const bf16*)AslU;
    const bf16* Bs = (const bf16*)BslU;
#pragma unroll
    for (int ks = 0; ks < 2; ks++) {
      int brow = wave * 16 + l16;
      bf16x8 bfr = *(const bf16x8*)(Bs + (size_t)(brow * 8 + ((ks * 4 + quad) ^ (brow & 7))) * 8);
#pragma unroll
      for (int mf = 0; mf < 4; mf++) {
        int arow = mf * 16 + l16;
        bf16x8 af = *(const bf16x8*)(As + (size_t)(arow * 8 + ((ks * 4 + quad) ^ (arow & 7))) * 8);
        acc[mf] = __builtin_amdgcn_mfma_f32_16x16x32_bf16(af, bfr, acc[mf], 0, 0, 0);
      }
    }
    __syncthreads();
  }
#pragma unroll
  for (int mf = 0; mf < 4; mf++) {
#pragma unroll
    for (int r = 0; r < 4; r++) {
      int row = mf * 16 + quad * 4 + r;
      int col = n0 + wave * 16 + l16;
      basep[((size_t)kz * 64 + row) * DIM + col] = acc[mf][r];
    }
  }
}

// ---------------- K6: MetaNet ----------------
__global__ void k_metanet(const float* __restrict__ basep,  // [4][64][768]
                          const float* __restrict__ b2,
                          const float* __restrict__ mw1, const float* __restrict__ mb1,
                          const float* __restrict__ mw2, const float* __restrict__ mb2,
                          float* __restrict__ coefs) {      // [64][8]
  __shared__ float bl[DIM];
  __shared__ float hl[192];
  int b = blockIdx.x, tid = threadIdx.x;   // 192 threads
  const size_t ZS = (size_t)64 * DIM;
  for (int i = tid; i < DIM; i += 192) {
    size_t o = (size_t)b * DIM + i;
    bl[i] = basep[o] + basep[ZS + o] + basep[2 * ZS + o] + basep[3 * ZS + o] + b2[i];
  }
  __syncthreads();
  float s = mb1[tid];
  for (int k = 0; k < DIM; k++) s += bl[k] * mw1[(size_t)k * 192 + tid];
  hl[tid] = fmaxf(s, 0.0f);
  __syncthreads();
  if (tid < NT) {
    float c = mb2[tid];
    for (int j = 0; j < 192; j++) c += hl[j] * mw2[(size_t)j * NT + tid];
    coefs[b * NT + tid] = c;
  }
}

// ---------------- K5: small GEMM, M=64: Y[mat] = Af(f32->bf16) @ WT[9+mat] ------------
__global__ __launch_bounds__(256, 2)
void k_gemm2(const float* __restrict__ Af,    // [64][768] f32
             const bf16* __restrict__ WT,
             float* __restrict__ Y) {         // [9][64][768]
  __shared__ uint4 AslU[64 * 8];
  __shared__ uint4 BslU[64 * 8];
  int n0  = blockIdx.x * 64;
  int mat = blockIdx.y;
  int tid = threadIdx.x, wave = tid >> 6, lane = tid & 63;
  int quad = lane >> 4, l16 = lane & 15;
  f32x4 acc[4] = {};
  const bf16* Wm = WT + (size_t)(9 + mat) * MSZ;
  for (int k0 = 0; k0 < DIM; k0 += 64) {
#pragma unroll
    for (int i = 0; i < 2; i++) {
      int g = tid + i * 256;
      int r = g >> 3, c = g & 7;
      const float* src = Af + (size_t)r * DIM + k0 + c * 8;
      float4 xa = ((const float4*)src)[0];
      float4 xb = ((const float4*)src)[1];
      BF8 o;
      o.h[0] = __float2bfloat16(xa.x); o.h[1] = __float2bfloat16(xa.y);
      o.h[2] = __float2bfloat16(xa.z); o.h[3] = __float2bfloat16(xa.w);
      o.h[4] = __float2bfloat16(xb.x); o.h[5] = __float2bfloat16(xb.y);
      o.h[6] = __float2bfloat16(xb.z); o.h[7] = __float2bfloat16(xb.w);
      AslU[r * 8 + (c ^ (r & 7))] = *(uint4*)&o;
      BslU[r * 8 + (c ^ (r & 7))] = *(const uint4*)(Wm + (size_t)(n0 + r) * DIM + k0 + c * 8);
    }
    __syncthreads();
    const bf16* As = (const bf16*)AslU;
    const bf16* Bs = (const bf16*)BslU;
#pragma unroll
    for (int ks = 0; ks < 2; ks++) {
      int brow = wave * 16 + l16;
      bf16x8 bfr = *(const bf16x8*)(Bs + (size_t)(brow * 8 + ((ks * 4 + quad) ^ (brow & 7))) * 8);
#pragma unroll
      for (int mf = 0; mf < 4; mf++) {
        int arow = mf * 16 + l16;
        bf16x8 af = *(const bf16x8*)(As + (size_t)(arow * 8 + ((ks * 4 + quad) ^ (arow & 7))) * 8);
        acc[mf] = __builtin_amdgcn_mfma_f32_16x16x32_bf16(af, bfr, acc[mf], 0, 0, 0);
      }
    }
    __syncthreads();
  }
#pragma unroll
  for (int mf = 0; mf < 4; mf++) {
#pragma unroll
    for (int r = 0; r < 4; r++) {
      int row = mf * 16 + quad * 4 + r;
      int col = n0 + wave * 16 + l16;
      Y[((size_t)mat * 64 + row) * DIM + col] = acc[mf][r];
    }
  }
}

// ---------------- K7: combine ----------------
__global__ void k_combine(const float* __restrict__ Y,
                          const float* __restrict__ coefs,
                          const float* __restrict__ b2,
                          const float* __restrict__ db2,
                          float* __restrict__ out) {
  int idx = blockIdx.x * 256 + threadIdx.x;
  int b = idx / DIM, e = idx % DIM;
  float v = Y[(size_t)b * DIM + e] + b2[e];
#pragma unroll
  for (int t = 0; t < NT; t++) {
    float c = coefs[b * NT + t];
    v += c * (Y[((size_t)(1 + t) * 64 + b) * DIM + e] + db2[(size_t)t * DIM + e]);
  }
  out[idx] = v;
}

extern "C" void kernel_launch(void* const* d_in, const int* in_sizes, int n_in,
                              void* d_out, int out_size, void* d_ws, size_t ws_size,
                              hipStream_t stream) {
  const float* x   = (const float*)d_in[0];
  const float* W1  = (const float*)d_in[1];
  const float* b1  = (const float*)d_in[2];
  const float* W2  = (const float*)d_in[3];
  const float* b2  = (const float*)d_in[4];
  const float* dW1 = (const float*)d_in[5];
  const float* db1 = (const float*)d_in[6];
  const float* dW2 = (const float*)d_in[7];
  const float* db2 = (const float*)d_in[8];
  const float* mw1 = (const float*)d_in[9];
  const float* mb1 = (const float*)d_in[10];
  const float* mw2 = (const float*)d_in[11];
  const float* mb2 = (const float*)d_in[12];
  float* out = (float*)d_out;
  (void)in_sizes; (void)n_in; (void)out_size; (void)ws_size;

  // workspace layout (bytes) — total ~49.4 MB
  char* ws = (char*)d_ws;
  bf16*  A_bf    = (bf16*) (ws);                 // 25,165,824
  bf16*  WT      = (bf16*) (ws + 25165824);      // 21,233,664 -> 46,399,488
  float* pooledA = (float*)(ws + 46399488);      //    196,608 -> 46,596,096
  float* pooledB = (float*)(ws + 46596096);      //    196,608 -> 46,792,704
  float* coefs   = (float*)(ws + 46792704);      //      2,048 -> 46,794,752
  float* basep   = (float*)(ws + 46794752);      //    786,432 -> 47,581,184
  float* Y       = (float*)(ws + 47581184);      //  1,769,472 -> 49,350,656

  k_prep<<<dim3(PREP_PATCH_BLOCKS + PREP_TRANS_BLOCKS), 256, 0, stream>>>(
      x, A_bf, W1, dW1, W2, dW2, WT);
  // phase A (1-block-per-CU probe)
  k_gemm_poolA<<<dim3(BATCH, DIM / 192), 512, 0, stream>>>(A_bf, WT, b1, pooledA);
  k_gemm2_ksplit<<<dim3(DIM / 64, 4), 256, 0, stream>>>(pooledA, WT, basep);
  k_metanet<<<dim3(BATCH), 192, 0, stream>>>(basep, b2, mw1, mb1, mw2, mb2, coefs);
  // phase B (inline mix, frozen r10 body)
  k_gemm_pool_mix<<<dim3(BATCH, DIM / 64), 256, 0, stream>>>(A_bf, WT, b1, db1, coefs, pooledB);
  k_gemm2<<<dim3(DIM / 64, 9), 256, 0, stream>>>(pooledB, WT, Y);
  k_combine<<<dim3((BATCH * DIM) / 256), 256, 0, stream>>>(Y, coefs, b2, db2, out);
}